// Round 2
// baseline (879.054 us; speedup 1.0000x reference)
//
#include <hip/hip_runtime.h>
#include <cstdint>
#include <cstddef>

// ---------------------------------------------------------------------------
// Cross_Self_attention: q=xWq+bq, k=xWk+bk, v=yWv+bv, P=softmax(qk^T),
// out = P @ (q*v).  B=8 S=2048 D=H=768, fp32 in/out, fp16 MFMA compute
// (fp16 over bf16 for 8x lower rounding error; same MFMA rate on gfx950).
//
// All matmuls use one bt-form GEMM: C[m,n] = sum_k A[m,k]*B[n,k]
// (both operands contiguous in k) -> m97-style 128x128 tile, BK=32,
// 4 waves, mfma_f32_16x16x32_f16, global_load_lds width=16 staging.
// ---------------------------------------------------------------------------

#define BM 128
#define BN 128
#define BK 32

using half8 = __attribute__((ext_vector_type(8))) _Float16;  // MFMA A/B frag
using half4 = __attribute__((ext_vector_type(4))) _Float16;
using f32x4 = __attribute__((ext_vector_type(4))) float;     // 4 fp32 acc

// ---------------- fp32 -> fp16 bulk convert (x, y) -------------------------
__global__ __launch_bounds__(256) void cvt_f32_f16(
    const float* __restrict__ in, _Float16* __restrict__ out, int n4) {
  int i = blockIdx.x * 256 + threadIdx.x;
  if (i >= n4) return;
  float4 v = ((const float4*)in)[i];
  half4 o = {(_Float16)v.x, (_Float16)v.y, (_Float16)v.z, (_Float16)v.w};
  *(half4*)&out[(size_t)i * 4] = o;
}

// ---------------- W[768,768] -> W^T fp16 (tiny, once per launch) -----------
__global__ __launch_bounds__(256) void transpose_cvt768(
    const float* __restrict__ W, _Float16* __restrict__ Wt) {
  int i = blockIdx.x * 256 + threadIdx.x;     // output index, [H*D)
  int h = i / 768, d = i - h * 768;
  Wt[i] = (_Float16)W[d * 768 + h];           // Wt[h][d] = W[d][h]
}

// ---------------- bt-form MFMA GEMM ----------------------------------------
// MODE 0: C(fp16)[m,n] = acc + bias[n]                       (q, k proj)
// MODE 1: gT write:  v=acc+bias[n]; g=v*qb[m,n];
//         gT[(b*768+n)*2048 + s] = fp16(g), b=m>>11, s=m&2047 (v proj + gate)
// MODE 2: C(fp32)[m,n] = acc, per-batch strides via blockIdx.z (scores, ctx)
template <int MODE>
__global__ __launch_bounds__(256) void gemm_bt(
    const _Float16* __restrict__ Ab, int ldA, long sA,
    const _Float16* __restrict__ Bb, int ldB, long sB,
    void* __restrict__ Cb, int ldc, long sC,
    int K, const float* __restrict__ bias, const _Float16* __restrict__ qb) {
  __shared__ __align__(16) _Float16 lA[BM * BK];
  __shared__ __align__(16) _Float16 lB[BN * BK];

  const int tid  = threadIdx.x;
  const int lane = tid & 63;
  const int quad = lane >> 4;
  const int l15  = lane & 15;
  const int wave = tid >> 6;
  const int wm = (wave >> 1) * 64;
  const int wn = (wave & 1) * 64;
  const long bm = (long)blockIdx.x * BM;
  const long bn = (long)blockIdx.y * BN;
  const _Float16* A = Ab + (long)blockIdx.z * sA;
  const _Float16* B = Bb + (long)blockIdx.z * sB;

  f32x4 acc[4][4] = {};

  // staging: 512 16B-chunks per tile, 2 per thread per operand.
  // chunk c -> row c>>2, col (c&3)*8 ; LDS dest = c*16B (wave-uniform+lane*16)
  const int c0 = tid,        r0 = c0 >> 2, k0c = (c0 & 3) * 8;
  const int c1 = 256 + tid,  r1 = c1 >> 2, k1c = (c1 & 3) * 8;
  const _Float16* gA0 = A + (size_t)(bm + r0) * ldA + k0c;
  const _Float16* gA1 = A + (size_t)(bm + r1) * ldA + k1c;
  const _Float16* gB0 = B + (size_t)(bn + r0) * ldB + k0c;
  const _Float16* gB1 = B + (size_t)(bn + r1) * ldB + k1c;

  for (int kk = 0; kk < K; kk += BK) {
    __syncthreads();   // previous iter's LDS reads done before overwrite
    __builtin_amdgcn_global_load_lds(
        (const __attribute__((address_space(1))) void*)(gA0 + kk),
        (__attribute__((address_space(3))) void*)&lA[c0 * 8], 16, 0, 0);
    __builtin_amdgcn_global_load_lds(
        (const __attribute__((address_space(1))) void*)(gA1 + kk),
        (__attribute__((address_space(3))) void*)&lA[c1 * 8], 16, 0, 0);
    __builtin_amdgcn_global_load_lds(
        (const __attribute__((address_space(1))) void*)(gB0 + kk),
        (__attribute__((address_space(3))) void*)&lB[c0 * 8], 16, 0, 0);
    __builtin_amdgcn_global_load_lds(
        (const __attribute__((address_space(1))) void*)(gB1 + kk),
        (__attribute__((address_space(3))) void*)&lB[c1 * 8], 16, 0, 0);
    __syncthreads();   // staging complete (drains vmcnt)

    half8 af[4], bfr[4];
#pragma unroll
    for (int i = 0; i < 4; i++) {
      af[i]  = *(const half8*)&lA[(wm + i * 16 + l15) * BK + quad * 8];
      bfr[i] = *(const half8*)&lB[(wn + i * 16 + l15) * BK + quad * 8];
    }
#pragma unroll
    for (int i = 0; i < 4; i++)
#pragma unroll
      for (int j = 0; j < 4; j++)
        acc[i][j] = __builtin_amdgcn_mfma_f32_16x16x32_f16(
            af[i], bfr[j], acc[i][j], 0, 0, 0);
  }

  // epilogue: C/D layout col = lane&15, row = quad*4 + reg  (m89-verified,
  // dtype-independent on gfx950)
#pragma unroll
  for (int i = 0; i < 4; i++) {
#pragma unroll
    for (int j = 0; j < 4; j++) {
#pragma unroll
      for (int r = 0; r < 4; r++) {
        long m = bm + wm + i * 16 + quad * 4 + r;
        long n = bn + wn + j * 16 + l15;
        float v = acc[i][j][r];
        if constexpr (MODE == 0) {
          v += bias[n];
          ((_Float16*)Cb)[m * ldc + n] = (_Float16)v;
        } else if constexpr (MODE == 1) {
          v += bias[n];
          float q = (float)qb[m * (long)ldc + n];
          long bb = m >> 11, s = m & 2047;
          ((_Float16*)Cb)[(bb * 768 + n) * 2048 + s] = (_Float16)(v * q);
        } else {
          ((float*)Cb + (long)blockIdx.z * sC)[m * ldc + n] = v;
        }
      }
    }
  }
}

// ---------------- row softmax: fp32 scores[row,2048] -> fp16 probs ---------
__global__ __launch_bounds__(256) void softmax_rows(
    const float* __restrict__ sc, _Float16* __restrict__ pr) {
  const int row = blockIdx.x;
  const float* x = sc + (size_t)row * 2048;
  const int t = threadIdx.x;
  float4 v0 = ((const float4*)x)[2 * t];
  float4 v1 = ((const float4*)x)[2 * t + 1];
  float e[8] = {v0.x, v0.y, v0.z, v0.w, v1.x, v1.y, v1.z, v1.w};

  float m = e[0];
#pragma unroll
  for (int i = 1; i < 8; i++) m = fmaxf(m, e[i]);
#pragma unroll
  for (int o = 32; o; o >>= 1) m = fmaxf(m, __shfl_xor(m, o, 64));
  __shared__ float red[4];
  if ((t & 63) == 0) red[t >> 6] = m;
  __syncthreads();
  m = fmaxf(fmaxf(red[0], red[1]), fmaxf(red[2], red[3]));

  float s = 0.f;
#pragma unroll
  for (int i = 0; i < 8; i++) { e[i] = __expf(e[i] - m); s += e[i]; }
#pragma unroll
  for (int o = 32; o; o >>= 1) s += __shfl_xor(s, o, 64);
  __syncthreads();   // everyone done reading red (max phase)
  if ((t & 63) == 0) red[t >> 6] = s;
  __syncthreads();
  s = red[0] + red[1] + red[2] + red[3];
  float inv = 1.0f / s;

  union { _Float16 h[8]; uint4 v; } o;
#pragma unroll
  for (int i = 0; i < 8; i++) o.h[i] = (_Float16)(e[i] * inv);
  ((uint4*)(pr + (size_t)row * 2048))[t] = o.v;
}

// ---------------------------------------------------------------------------
extern "C" void kernel_launch(void* const* d_in, const int* in_sizes, int n_in,
                              void* d_out, int out_size, void* d_ws, size_t ws_size,
                              hipStream_t stream) {
  const float* x  = (const float*)d_in[0];
  const float* y  = (const float*)d_in[1];
  const float* Wq = (const float*)d_in[2];
  const float* bq = (const float*)d_in[3];
  const float* Wk = (const float*)d_in[4];
  const float* bk = (const float*)d_in[5];
  const float* Wv = (const float*)d_in[6];
  const float* bv = (const float*)d_in[7];
  float* out = (float*)d_out;

  const int S = 2048, D = 768, H = 768;
  char* ws = (char*)d_ws;
  // persistent region: qb, kb, gT (25.17 MB each)
  _Float16* qb  = (_Float16*)(ws + 0);
  _Float16* kb  = (_Float16*)(ws + 25165824);
  _Float16* gT  = (_Float16*)(ws + 50331648);
  // staging region (dead after projections), aliased by scores afterwards
  _Float16* xb  = (_Float16*)(ws + 75497472);
  _Float16* yb  = (_Float16*)(ws + 100663296);
  _Float16* WtQ = (_Float16*)(ws + 125829120);
  _Float16* WtK = (_Float16*)(ws + 127008768);
  _Float16* WtV = (_Float16*)(ws + 128188416);
  float* scores = (float*)(ws + 75497472);
  const bool full = ws_size >= 276824064ull;   // constant per run: capture-safe
  _Float16* probs = full ? (_Float16*)(ws + 209715200)
                         : (_Float16*)(ws + 92274688);

  // 1) convert inputs to fp16 (+ transpose weights so every GEMM is bt-form)
  cvt_f32_f16<<<12288, 256, 0, stream>>>(x, xb, 3145728);
  cvt_f32_f16<<<12288, 256, 0, stream>>>(y, yb, 3145728);
  transpose_cvt768<<<2304, 256, 0, stream>>>(Wq, WtQ);
  transpose_cvt768<<<2304, 256, 0, stream>>>(Wk, WtK);
  transpose_cvt768<<<2304, 256, 0, stream>>>(Wv, WtV);

  // 2) projections: q, k (fp16), then v fused with gate g = q*v -> gT [b,H,S]
  gemm_bt<0><<<dim3(128, 6, 1), 256, 0, stream>>>(xb, D, 0, WtQ, D, 0, qb, H, 0, D, bq, nullptr);
  gemm_bt<0><<<dim3(128, 6, 1), 256, 0, stream>>>(xb, D, 0, WtK, D, 0, kb, H, 0, D, bk, nullptr);
  gemm_bt<1><<<dim3(128, 6, 1), 256, 0, stream>>>(yb, D, 0, WtV, D, 0, gT, H, 0, D, bv, qb);

  // 3) attention: scores = q k^T (fp32), softmax -> fp16, out = P gT^T (fp32)
  if (full) {
    gemm_bt<2><<<dim3(16, 16, 8), 256, 0, stream>>>(
        qb, H, (long)S * H, kb, H, (long)S * H, scores, S, (long)S * S, H, nullptr, nullptr);
    softmax_rows<<<16384, 256, 0, stream>>>(scores, probs);
    gemm_bt<2><<<dim3(16, 6, 8), 256, 0, stream>>>(
        probs, S, (long)S * S, gT, S, (long)H * S, out, H, (long)S * H, S, nullptr, nullptr);
  } else {
    for (int b = 0; b < 8; b++) {
      gemm_bt<2><<<dim3(16, 16, 1), 256, 0, stream>>>(
          qb + (long)b * S * H, H, 0, kb + (long)b * S * H, H, 0, scores, S, 0, H, nullptr, nullptr);
      softmax_rows<<<2048, 256, 0, stream>>>(scores, probs);
      gemm_bt<2><<<dim3(16, 6, 1), 256, 0, stream>>>(
          probs, S, 0, gT + (long)b * H * S, S, 0, out + (long)b * S * H, H, 0, S, nullptr, nullptr);
    }
  }
}

// Round 3
// 848.763 us; speedup vs baseline: 1.0357x; 1.0357x over previous
//
#include <hip/hip_runtime.h>
#include <cstdint>
#include <cstddef>

// ---------------------------------------------------------------------------
// Cross_Self_attention: q=xWq+bq, k=xWk+bk, v=yWv+bv, P=softmax(qk^T),
// out = P @ (q*v).  B=8 S=2048 D=H=768, fp32 in/out, fp16 MFMA compute.
//
// bt-form GEMM (both operands k-contiguous), m97 structure: 128x128 tile,
// BK=32, 4 waves, mfma_f32_16x16x32_f16, global_load_lds width=16.
// MODE 1 (v-proj + gate -> gT) now transposes the 64x64 wave tile through
// LDS so gT stores are 16B-coalesced (was: 64 scattered 2B stores/thread).
// q+k projections fused into one N=1536 GEMM (x staged once, 2x blocks).
// ---------------------------------------------------------------------------

#define BM 128
#define BN 128
#define BK 32

using half8 = __attribute__((ext_vector_type(8))) _Float16;  // MFMA A/B frag
using half4 = __attribute__((ext_vector_type(4))) _Float16;
using f32x4 = __attribute__((ext_vector_type(4))) float;     // 4 fp32 acc

// ---------------- fp32 -> fp16 bulk convert (x and y in one dispatch) ------
__global__ __launch_bounds__(256) void cvt2_f32_f16(
    const float* __restrict__ a, const float* __restrict__ b,
    _Float16* __restrict__ oa, _Float16* __restrict__ ob, int n4) {
  const float* in = blockIdx.y ? b : a;
  _Float16* out = blockIdx.y ? ob : oa;
  int i = blockIdx.x * 256 + threadIdx.x;
  if (i >= n4) return;
  float4 v = ((const float4*)in)[i];
  half4 o = {(_Float16)v.x, (_Float16)v.y, (_Float16)v.z, (_Float16)v.w};
  *(half4*)&out[(size_t)i * 4] = o;
}

// ---------------- all three W[768,768] -> W^T fp16 in one dispatch ---------
// Wt base must have Q,K,V contiguous (589824 elements apart).
__global__ __launch_bounds__(256) void tr3_cvt768(
    const float* __restrict__ Wq, const float* __restrict__ Wk,
    const float* __restrict__ Wv, _Float16* __restrict__ Wt) {
  const float* W = (blockIdx.y == 0) ? Wq : (blockIdx.y == 1) ? Wk : Wv;
  _Float16* o = Wt + (size_t)blockIdx.y * 589824;
  int i = blockIdx.x * 256 + threadIdx.x;
  int h = i / 768, d = i - h * 768;
  o[i] = (_Float16)W[d * 768 + h];             // Wt[h][d] = W[d][h]
}

// ---------------- bt-form MFMA GEMM ----------------------------------------
// MODE 1: v=acc+bias[n]; g=v*qb[m,n]; gT[(b*768+n)*2048+s]=fp16(g)
//         (LDS-transposed, coalesced 16B stores)
// MODE 2: C(fp32)[m,n]=acc, per-batch strides via blockIdx.z (scores, ctx)
// MODE 3: fused q|k proj: n<768 -> Cb=qb (bias), else Cb2=kb (bias2)
template <int MODE>
__global__ __launch_bounds__(256) void gemm_bt(
    const _Float16* __restrict__ Ab, int ldA, long sA,
    const _Float16* __restrict__ Bb, int ldB, long sB,
    void* __restrict__ Cb, int ldc, long sC,
    int K, const float* __restrict__ bias, const _Float16* __restrict__ qb,
    const float* __restrict__ bias2, void* __restrict__ Cb2) {
  __shared__ __align__(16) _Float16 lA[BM * BK];
  __shared__ __align__(16) _Float16 lB[BN * BK];

  const int tid  = threadIdx.x;
  const int lane = tid & 63;
  const int quad = lane >> 4;
  const int l15  = lane & 15;
  const int wave = tid >> 6;
  const int wm = (wave >> 1) * 64;
  const int wn = (wave & 1) * 64;
  const long bm = (long)blockIdx.x * BM;
  const long bn = (long)blockIdx.y * BN;
  const _Float16* A = Ab + (long)blockIdx.z * sA;
  const _Float16* B = Bb + (long)blockIdx.z * sB;

  f32x4 acc[4][4] = {};

  // staging: 512 16B-chunks per tile, 2 per thread per operand.
  const int c0 = tid,        r0 = c0 >> 2, k0c = (c0 & 3) * 8;
  const int c1 = 256 + tid,  r1 = c1 >> 2, k1c = (c1 & 3) * 8;
  const _Float16* gA0 = A + (size_t)(bm + r0) * ldA + k0c;
  const _Float16* gA1 = A + (size_t)(bm + r1) * ldA + k1c;
  const _Float16* gB0 = B + (size_t)(bn + r0) * ldB + k0c;
  const _Float16* gB1 = B + (size_t)(bn + r1) * ldB + k1c;

  for (int kk = 0; kk < K; kk += BK) {
    __syncthreads();
    __builtin_amdgcn_global_load_lds(
        (const __attribute__((address_space(1))) void*)(gA0 + kk),
        (__attribute__((address_space(3))) void*)&lA[c0 * 8], 16, 0, 0);
    __builtin_amdgcn_global_load_lds(
        (const __attribute__((address_space(1))) void*)(gA1 + kk),
        (__attribute__((address_space(3))) void*)&lA[c1 * 8], 16, 0, 0);
    __builtin_amdgcn_global_load_lds(
        (const __attribute__((address_space(1))) void*)(gB0 + kk),
        (__attribute__((address_space(3))) void*)&lB[c0 * 8], 16, 0, 0);
    __builtin_amdgcn_global_load_lds(
        (const __attribute__((address_space(1))) void*)(gB1 + kk),
        (__attribute__((address_space(3))) void*)&lB[c1 * 8], 16, 0, 0);
    __syncthreads();

    half8 af[4], bfr[4];
#pragma unroll
    for (int i = 0; i < 4; i++) {
      af[i]  = *(const half8*)&lA[(wm + i * 16 + l15) * BK + quad * 8];
      bfr[i] = *(const half8*)&lB[(wn + i * 16 + l15) * BK + quad * 8];
    }
#pragma unroll
    for (int i = 0; i < 4; i++)
#pragma unroll
      for (int j = 0; j < 4; j++)
        acc[i][j] = __builtin_amdgcn_mfma_f32_16x16x32_f16(
            af[i], bfr[j], acc[i][j], 0, 0, 0);
  }

  // epilogue: C/D layout col = lane&15, row = quad*4 + reg (m89-verified)
  if constexpr (MODE == 1) {
    // transpose 64x64 wave tile via LDS -> coalesced gT stores.
    // per wave: 32 n-rows x 64 m halfs, stride 72 halfs (bank-spread pad).
    __shared__ __align__(16) _Float16 xp[4 * 32 * 72];   // 18 KB
    _Float16* xw = &xp[wave * 2304];
    const long sbase = (bm & 2047) + wm;   // tiles never straddle a batch
    const long bb = bm >> 11;
    const long hbase = bn + wn;
#pragma unroll
    for (int jh = 0; jh < 2; jh++) {       // n halves: j in {2jh, 2jh+1}
      __syncthreads();                     // WAR between rounds
#pragma unroll
      for (int j2 = 0; j2 < 2; j2++) {
        const int j = jh * 2 + j2;
        const long n_g = hbase + j * 16 + l15;
        const float bsv = bias[n_g];
#pragma unroll
        for (int i = 0; i < 4; i++) {
          half4 pk;
#pragma unroll
          for (int r = 0; r < 4; r++) {
            long m_g = bm + wm + i * 16 + quad * 4 + r;
            float v = acc[i][j][r] + bsv;
            float q = (float)qb[m_g * (long)ldc + n_g];
            pk[r] = (_Float16)(v * q);
          }
          *(half4*)&xw[(j2 * 16 + l15) * 72 + i * 16 + quad * 4] = pk;
        }
      }
      __syncthreads();                     // within-wave RAW (and symmetry)
#pragma unroll
      for (int t = 0; t < 4; t++) {        // 8 rows x (8 lanes x 16B) each
        const int n_r = t * 8 + (lane >> 3);
        const int m8 = (lane & 7) * 8;
        half8 vv = *(const half8*)&xw[n_r * 72 + m8];
        *(half8*)&((_Float16*)Cb)[(bb * 768 + hbase + 32 * jh + n_r) * 2048 +
                                  sbase + m8] = vv;
      }
    }
  } else {
#pragma unroll
    for (int i = 0; i < 4; i++) {
#pragma unroll
      for (int j = 0; j < 4; j++) {
#pragma unroll
        for (int r = 0; r < 4; r++) {
          long m = bm + wm + i * 16 + quad * 4 + r;
          long n = bn + wn + j * 16 + l15;
          float v = acc[i][j][r];
          if constexpr (MODE == 3) {
            const bool isq = (bn < 768);                 // block-uniform
            long nn = isq ? n : n - 768;
            v += (isq ? bias : bias2)[nn];
            _Float16* dst = (_Float16*)(isq ? Cb : Cb2);
            dst[m * ldc + nn] = (_Float16)v;
          } else {
            ((float*)Cb + (long)blockIdx.z * sC)[m * ldc + n] = v;
          }
        }
      }
    }
  }
}

// ---------------- row softmax: fp32 scores[row,2048] -> fp16 probs ---------
__global__ __launch_bounds__(256) void softmax_rows(
    const float* __restrict__ sc, _Float16* __restrict__ pr) {
  const int row = blockIdx.x;
  const float* x = sc + (size_t)row * 2048;
  const int t = threadIdx.x;
  float4 v0 = ((const float4*)x)[2 * t];
  float4 v1 = ((const float4*)x)[2 * t + 1];
  float e[8] = {v0.x, v0.y, v0.z, v0.w, v1.x, v1.y, v1.z, v1.w};

  float m = e[0];
#pragma unroll
  for (int i = 1; i < 8; i++) m = fmaxf(m, e[i]);
#pragma unroll
  for (int o = 32; o; o >>= 1) m = fmaxf(m, __shfl_xor(m, o, 64));
  __shared__ float red[4];
  if ((t & 63) == 0) red[t >> 6] = m;
  __syncthreads();
  m = fmaxf(fmaxf(red[0], red[1]), fmaxf(red[2], red[3]));

  float s = 0.f;
#pragma unroll
  for (int i = 0; i < 8; i++) { e[i] = __expf(e[i] - m); s += e[i]; }
#pragma unroll
  for (int o = 32; o; o >>= 1) s += __shfl_xor(s, o, 64);
  __syncthreads();
  if ((t & 63) == 0) red[t >> 6] = s;
  __syncthreads();
  s = red[0] + red[1] + red[2] + red[3];
  float inv = 1.0f / s;

  union { _Float16 h[8]; uint4 v; } o;
#pragma unroll
  for (int i = 0; i < 8; i++) o.h[i] = (_Float16)(e[i] * inv);
  ((uint4*)(pr + (size_t)row * 2048))[t] = o.v;
}

// ---------------------------------------------------------------------------
extern "C" void kernel_launch(void* const* d_in, const int* in_sizes, int n_in,
                              void* d_out, int out_size, void* d_ws, size_t ws_size,
                              hipStream_t stream) {
  const float* x  = (const float*)d_in[0];
  const float* y  = (const float*)d_in[1];
  const float* Wq = (const float*)d_in[2];
  const float* bq = (const float*)d_in[3];
  const float* Wk = (const float*)d_in[4];
  const float* bk = (const float*)d_in[5];
  const float* Wv = (const float*)d_in[6];
  const float* bv = (const float*)d_in[7];
  float* out = (float*)d_out;

  const int S = 2048, D = 768, H = 768;
  char* ws = (char*)d_ws;
  // persistent region: qb, kb, gT (25.17 MB each)
  _Float16* qb  = (_Float16*)(ws + 0);
  _Float16* kb  = (_Float16*)(ws + 25165824);
  _Float16* gT  = (_Float16*)(ws + 50331648);
  // staging region (dead after projections), aliased by scores afterwards
  _Float16* xb  = (_Float16*)(ws + 75497472);
  _Float16* yb  = (_Float16*)(ws + 100663296);
  _Float16* WtQ = (_Float16*)(ws + 125829120);   // Q,K,V contiguous!
  _Float16* WtV = (_Float16*)(ws + 128188416);
  float* scores = (float*)(ws + 75497472);
  const bool full = ws_size >= 276824064ull;   // constant per run: capture-safe
  _Float16* probs = full ? (_Float16*)(ws + 209715200)
                         : (_Float16*)(ws + 92274688);

  // 1) prep: fp16 casts + weight transposes (2 dispatches)
  cvt2_f32_f16<<<dim3(12288, 2), 256, 0, stream>>>(x, y, xb, yb, 3145728);
  tr3_cvt768<<<dim3(2304, 3), 256, 0, stream>>>(Wq, Wk, Wv, WtQ);

  // 2) projections: fused q|k (N=1536), then v fused with gate -> gT [b,H,S]
  gemm_bt<3><<<dim3(128, 12, 1), 256, 0, stream>>>(
      xb, D, 0, WtQ, D, 0, qb, H, 0, D, bq, nullptr, bk, kb);
  gemm_bt<1><<<dim3(128, 6, 1), 256, 0, stream>>>(
      yb, D, 0, WtV, D, 0, gT, H, 0, D, bv, qb, nullptr, nullptr);

  // 3) attention: scores = q k^T (fp32), softmax -> fp16, out = P gT^T (fp32)
  if (full) {
    gemm_bt<2><<<dim3(16, 16, 8), 256, 0, stream>>>(
        qb, H, (long)S * H, kb, H, (long)S * H, scores, S, (long)S * S, H,
        nullptr, nullptr, nullptr, nullptr);
    softmax_rows<<<16384, 256, 0, stream>>>(scores, probs);
    gemm_bt<2><<<dim3(16, 6, 8), 256, 0, stream>>>(
        probs, S, (long)S * S, gT, S, (long)H * S, out, H, (long)S * H, S,
        nullptr, nullptr, nullptr, nullptr);
  } else {
    for (int b = 0; b < 8; b++) {
      gemm_bt<2><<<dim3(16, 16, 1), 256, 0, stream>>>(
          qb + (long)b * S * H, H, 0, kb + (long)b * S * H, H, 0, scores, S, 0,
          H, nullptr, nullptr, nullptr, nullptr);
      softmax_rows<<<2048, 256, 0, stream>>>(scores, probs);
      gemm_bt<2><<<dim3(16, 6, 1), 256, 0, stream>>>(
          probs, S, 0, gT + (long)b * H * S, S, 0, out + (long)b * S * H, H, 0,
          S, nullptr, nullptr, nullptr, nullptr);
    }
  }
}

// Round 4
// 449.400 us; speedup vs baseline: 1.9561x; 1.8887x over previous
//
#include <hip/hip_runtime.h>
#include <cstdint>
#include <cstddef>

// ---------------------------------------------------------------------------
// Cross_Self_attention: q=xWq+bq, k=xWk+bk, v=yWv+bv, P=softmax(qk^T),
// out = P @ (q*v).  B=8 S=2048 D=H=768, fp32 in/out, fp16 MFMA compute.
//
// Workspace tiers (ws_size is constant per run -> branch is capture-safe):
//  Tier A (ws >= 209.7MB): all-batch two-pass. scores fp32 [8,2048,2048]
//    aliases the dead xb/yb/Wt staging region; softmax writes fp16 probs
//    IN-PLACE into the first 4KB of each 8KB score row (pitch 4096 halfs).
//  Tier C (else, >= 129.4MB): 4 rounds x 2 batches, same in-place trick.
// ---------------------------------------------------------------------------

#define BM 128
#define BN 128
#define BK 32

using half8 = __attribute__((ext_vector_type(8))) _Float16;  // MFMA A/B frag
using half4 = __attribute__((ext_vector_type(4))) _Float16;
using f32x4 = __attribute__((ext_vector_type(4))) float;     // 4 fp32 acc

// ---------------- fp32 -> fp16 bulk convert (x and y in one dispatch) ------
__global__ __launch_bounds__(256) void cvt2_f32_f16(
    const float* __restrict__ a, const float* __restrict__ b,
    _Float16* __restrict__ oa, _Float16* __restrict__ ob, int n4) {
  const float* in = blockIdx.y ? b : a;
  _Float16* out = blockIdx.y ? ob : oa;
  int i = blockIdx.x * 256 + threadIdx.x;
  if (i >= n4) return;
  float4 v = ((const float4*)in)[i];
  half4 o = {(_Float16)v.x, (_Float16)v.y, (_Float16)v.z, (_Float16)v.w};
  *(half4*)&out[(size_t)i * 4] = o;
}

// ---------------- all three W[768,768] -> W^T fp16 in one dispatch ---------
__global__ __launch_bounds__(256) void tr3_cvt768(
    const float* __restrict__ Wq, const float* __restrict__ Wk,
    const float* __restrict__ Wv, _Float16* __restrict__ Wt) {
  const float* W = (blockIdx.y == 0) ? Wq : (blockIdx.y == 1) ? Wk : Wv;
  _Float16* o = Wt + (size_t)blockIdx.y * 589824;
  int i = blockIdx.x * 256 + threadIdx.x;
  int h = i / 768, d = i - h * 768;
  o[i] = (_Float16)W[d * 768 + h];             // Wt[h][d] = W[d][h]
}

// ---------------- bt-form MFMA GEMM ----------------------------------------
// MODE 1: v=acc+bias[n]; g=v*qb[m,n]; gT[(b*768+n)*2048+s]=fp16(g)
//         (LDS-transposed, coalesced 16B stores)
// MODE 2: C(fp32)[m,n]=acc, per-batch strides via blockIdx.z (scores, ctx)
// MODE 3: fused q|k proj: n<768 -> Cb=qb (bias), else Cb2=kb (bias2)
template <int MODE>
__global__ __launch_bounds__(256) void gemm_bt(
    const _Float16* __restrict__ Ab, int ldA, long sA,
    const _Float16* __restrict__ Bb, int ldB, long sB,
    void* __restrict__ Cb, int ldc, long sC,
    int K, const float* __restrict__ bias, const _Float16* __restrict__ qb,
    const float* __restrict__ bias2, void* __restrict__ Cb2) {
  __shared__ __align__(16) _Float16 lA[BM * BK];
  __shared__ __align__(16) _Float16 lB[BN * BK];

  const int tid  = threadIdx.x;
  const int lane = tid & 63;
  const int quad = lane >> 4;
  const int l15  = lane & 15;
  const int wave = tid >> 6;
  const int wm = (wave >> 1) * 64;
  const int wn = (wave & 1) * 64;
  const long bm = (long)blockIdx.x * BM;
  const long bn = (long)blockIdx.y * BN;
  const _Float16* A = Ab + (long)blockIdx.z * sA;
  const _Float16* B = Bb + (long)blockIdx.z * sB;

  f32x4 acc[4][4] = {};

  // staging: 512 16B-chunks per tile, 2 per thread per operand.
  const int c0 = tid,        r0 = c0 >> 2, k0c = (c0 & 3) * 8;
  const int c1 = 256 + tid,  r1 = c1 >> 2, k1c = (c1 & 3) * 8;
  const _Float16* gA0 = A + (size_t)(bm + r0) * ldA + k0c;
  const _Float16* gA1 = A + (size_t)(bm + r1) * ldA + k1c;
  const _Float16* gB0 = B + (size_t)(bn + r0) * ldB + k0c;
  const _Float16* gB1 = B + (size_t)(bn + r1) * ldB + k1c;

  for (int kk = 0; kk < K; kk += BK) {
    __syncthreads();
    __builtin_amdgcn_global_load_lds(
        (const __attribute__((address_space(1))) void*)(gA0 + kk),
        (__attribute__((address_space(3))) void*)&lA[c0 * 8], 16, 0, 0);
    __builtin_amdgcn_global_load_lds(
        (const __attribute__((address_space(1))) void*)(gA1 + kk),
        (__attribute__((address_space(3))) void*)&lA[c1 * 8], 16, 0, 0);
    __builtin_amdgcn_global_load_lds(
        (const __attribute__((address_space(1))) void*)(gB0 + kk),
        (__attribute__((address_space(3))) void*)&lB[c0 * 8], 16, 0, 0);
    __builtin_amdgcn_global_load_lds(
        (const __attribute__((address_space(1))) void*)(gB1 + kk),
        (__attribute__((address_space(3))) void*)&lB[c1 * 8], 16, 0, 0);
    __syncthreads();

    half8 af[4], bfr[4];
#pragma unroll
    for (int i = 0; i < 4; i++) {
      af[i]  = *(const half8*)&lA[(wm + i * 16 + l15) * BK + quad * 8];
      bfr[i] = *(const half8*)&lB[(wn + i * 16 + l15) * BK + quad * 8];
    }
#pragma unroll
    for (int i = 0; i < 4; i++)
#pragma unroll
      for (int j = 0; j < 4; j++)
        acc[i][j] = __builtin_amdgcn_mfma_f32_16x16x32_f16(
            af[i], bfr[j], acc[i][j], 0, 0, 0);
  }

  // epilogue: C/D layout col = lane&15, row = quad*4 + reg (m89-verified)
  if constexpr (MODE == 1) {
    // transpose 64x64 wave tile via LDS -> coalesced gT stores.
    __shared__ __align__(16) _Float16 xp[4 * 32 * 72];   // 18 KB
    _Float16* xw = &xp[wave * 2304];
    const long sbase = (bm & 2047) + wm;   // tiles never straddle a batch
    const long bb = bm >> 11;
    const long hbase = bn + wn;
#pragma unroll
    for (int jh = 0; jh < 2; jh++) {       // n halves: j in {2jh, 2jh+1}
      __syncthreads();                     // WAR between rounds
#pragma unroll
      for (int j2 = 0; j2 < 2; j2++) {
        const int j = jh * 2 + j2;
        const long n_g = hbase + j * 16 + l15;
        const float bsv = bias[n_g];
#pragma unroll
        for (int i = 0; i < 4; i++) {
          half4 pk;
#pragma unroll
          for (int r = 0; r < 4; r++) {
            long m_g = bm + wm + i * 16 + quad * 4 + r;
            float v = acc[i][j][r] + bsv;
            float q = (float)qb[m_g * (long)ldc + n_g];
            pk[r] = (_Float16)(v * q);
          }
          *(half4*)&xw[(j2 * 16 + l15) * 72 + i * 16 + quad * 4] = pk;
        }
      }
      __syncthreads();                     // within-wave RAW
#pragma unroll
      for (int t = 0; t < 4; t++) {        // 8 rows x (8 lanes x 16B) each
        const int n_r = t * 8 + (lane >> 3);
        const int m8 = (lane & 7) * 8;
        half8 vv = *(const half8*)&xw[n_r * 72 + m8];
        *(half8*)&((_Float16*)Cb)[(bb * 768 + hbase + 32 * jh + n_r) * 2048 +
                                  sbase + m8] = vv;
      }
    }
  } else {
#pragma unroll
    for (int i = 0; i < 4; i++) {
#pragma unroll
      for (int j = 0; j < 4; j++) {
#pragma unroll
        for (int r = 0; r < 4; r++) {
          long m = bm + wm + i * 16 + quad * 4 + r;
          long n = bn + wn + j * 16 + l15;
          float v = acc[i][j][r];
          if constexpr (MODE == 3) {
            const bool isq = (bn < 768);                 // block-uniform
            long nn = isq ? n : n - 768;
            v += (isq ? bias : bias2)[nn];
            _Float16* dst = (_Float16*)(isq ? Cb : Cb2);
            dst[m * ldc + nn] = (_Float16)v;
          } else {
            ((float*)Cb + (long)blockIdx.z * sC)[m * ldc + n] = v;
          }
        }
      }
    }
  }
}

// ---------------- row softmax: fp32 scores[row,2048] -> fp16 probs ---------
// pr may alias sc (in-place): all of a block's loads complete before its
// first __syncthreads, stores happen after the last one, and a block only
// touches its own row.
__global__ __launch_bounds__(256) void softmax_rows(
    const float* __restrict__ sc, _Float16* __restrict__ pr, int prPitch) {
  const int row = blockIdx.x;
  const float* x = sc + (size_t)row * 2048;
  const int t = threadIdx.x;
  float4 v0 = ((const float4*)x)[2 * t];
  float4 v1 = ((const float4*)x)[2 * t + 1];
  float e[8] = {v0.x, v0.y, v0.z, v0.w, v1.x, v1.y, v1.z, v1.w};

  float m = e[0];
#pragma unroll
  for (int i = 1; i < 8; i++) m = fmaxf(m, e[i]);
#pragma unroll
  for (int o = 32; o; o >>= 1) m = fmaxf(m, __shfl_xor(m, o, 64));
  __shared__ float red[4];
  if ((t & 63) == 0) red[t >> 6] = m;
  __syncthreads();
  m = fmaxf(fmaxf(red[0], red[1]), fmaxf(red[2], red[3]));

  float s = 0.f;
#pragma unroll
  for (int i = 0; i < 8; i++) { e[i] = __expf(e[i] - m); s += e[i]; }
#pragma unroll
  for (int o = 32; o; o >>= 1) s += __shfl_xor(s, o, 64);
  __syncthreads();
  if ((t & 63) == 0) red[t >> 6] = s;
  __syncthreads();
  s = red[0] + red[1] + red[2] + red[3];
  float inv = 1.0f / s;

  union { _Float16 h[8]; uint4 v; } o;
#pragma unroll
  for (int i = 0; i < 8; i++) o.h[i] = (_Float16)(e[i] * inv);
  ((uint4*)(pr + (size_t)row * prPitch))[t] = o.v;
}

// ---------------------------------------------------------------------------
extern "C" void kernel_launch(void* const* d_in, const int* in_sizes, int n_in,
                              void* d_out, int out_size, void* d_ws, size_t ws_size,
                              hipStream_t stream) {
  const float* x  = (const float*)d_in[0];
  const float* y  = (const float*)d_in[1];
  const float* Wq = (const float*)d_in[2];
  const float* bq = (const float*)d_in[3];
  const float* Wk = (const float*)d_in[4];
  const float* bk = (const float*)d_in[5];
  const float* Wv = (const float*)d_in[6];
  const float* bv = (const float*)d_in[7];
  float* out = (float*)d_out;

  const int S = 2048, D = 768, H = 768;
  const long SH = (long)S * H;          // 1572864
  char* ws = (char*)d_ws;
  // persistent: qb, kb, gT (25.17 MB each)
  _Float16* qb  = (_Float16*)(ws + 0);
  _Float16* kb  = (_Float16*)(ws + 25165824);
  _Float16* gT  = (_Float16*)(ws + 50331648);
  // staging (dead after projections; scores aliases it afterwards)
  _Float16* xb  = (_Float16*)(ws + 75497472);
  _Float16* yb  = (_Float16*)(ws + 100663296);
  _Float16* WtQ = (_Float16*)(ws + 125829120);   // Q,K,V contiguous
  _Float16* WtV = WtQ + 2 * 589824;
  float* scores = (float*)(ws + 75497472);

  // 1) prep
  cvt2_f32_f16<<<dim3(12288, 2), 256, 0, stream>>>(x, y, xb, yb, 3145728);
  tr3_cvt768<<<dim3(2304, 3), 256, 0, stream>>>(Wq, Wk, Wv, WtQ);

  // 2) projections: fused q|k (N=1536), then v fused with gate -> gT [b,H,S]
  gemm_bt<3><<<dim3(128, 12, 1), 256, 0, stream>>>(
      xb, D, 0, WtQ, D, 0, qb, H, 0, D, bq, nullptr, bk, kb);
  gemm_bt<1><<<dim3(128, 6, 1), 256, 0, stream>>>(
      yb, D, 0, WtV, D, 0, gT, H, 0, D, bv, qb, nullptr, nullptr);

  // 3) attention. probs live in-place in scores rows: fp16 pitch 4096 halfs.
  _Float16* probs = (_Float16*)scores;
  if (ws_size >= 209715200ull) {        // Tier A: all 8 batches at once
    gemm_bt<2><<<dim3(16, 16, 8), 256, 0, stream>>>(
        qb, H, SH, kb, H, SH, scores, S, (long)S * S, H,
        nullptr, nullptr, nullptr, nullptr);
    softmax_rows<<<16384, 256, 0, stream>>>(scores, probs, 4096);
    gemm_bt<2><<<dim3(16, 6, 8), 256, 0, stream>>>(
        probs, 4096, (long)S * 4096, gT, S, SH, out, H, SH, S,
        nullptr, nullptr, nullptr, nullptr);
  } else {                              // Tier C: 4 rounds x 2 batches
    for (int r = 0; r < 4; r++) {
      const long b0 = 2 * r;
      gemm_bt<2><<<dim3(16, 16, 2), 256, 0, stream>>>(
          qb + b0 * SH, H, SH, kb + b0 * SH, H, SH, scores, S, (long)S * S, H,
          nullptr, nullptr, nullptr, nullptr);
      softmax_rows<<<4096, 256, 0, stream>>>(scores, probs, 4096);
      gemm_bt<2><<<dim3(16, 6, 2), 256, 0, stream>>>(
          probs, 4096, (long)S * 4096, gT + b0 * SH, S, SH,
          out + b0 * SH, H, SH, S, nullptr, nullptr, nullptr, nullptr);
    }
  }
}